// Round 2
// baseline (740.956 us; speedup 1.0000x reference)
//
#include <hip/hip_runtime.h>

#define NTOK 49
#define DIM 192
#define HEADS 6
#define NWIN 64
#define NBLK 4096

typedef unsigned short u16;
typedef short bf16x8 __attribute__((ext_vector_type(8)));
typedef unsigned short u16x4 __attribute__((ext_vector_type(4)));
typedef unsigned short u16x8 __attribute__((ext_vector_type(8)));
typedef float f32x4 __attribute__((ext_vector_type(4)));

#define QKVW_ELEMS (3 * DIM * DIM)   // 110592
#define PROJW_ELEMS (DIM * DIM)      // 36864

// workspace: [0, 294912) bf16 weights ; [294912, +37632) rope table
// table: [H][49][16] float2 (cos,sin) per pair == [H][49][8] float4
#define TB_OFF_BYTES ((QKVW_ELEMS + PROJW_ELEMS) * 2)    // 294912
#define TB_QUADS     (HEADS * NTOK * 8)                   // 2352 float4

// LDS map (bytes), total 52256 -> 3 blocks/CU (52736 granulated * 3 = 158208 <= 163840)
//  [0,25600)      xs [64][200] u16 staging + pass-B B-frag source (dead after pass B)
//  [0,19600)      ao [49][200] u16 attn-out (overlays xs during attn/proj)
//  [25600,51200)  bounce [64][200] u16 (pass A only)
//  [25600,45200)  ks [49][200] u16 (pass B -> attn; overwrites bounce)
//  [45200,52256)  ps [49][72] u16
#define XS_OFF 0
#define AO_OFF 0
#define BN_OFF 25600
#define KS_OFF 25600
#define PS_OFF 45200
#define LDS_TOTAL 52256

__device__ __forceinline__ float bf2f(u16 u) {
    union { unsigned int i; float f; } x; x.i = ((unsigned int)u) << 16; return x.f;
}
__device__ __forceinline__ u16 f2bf(float f) {
    union { float f; unsigned int u; } x; x.f = f;
    unsigned int u = x.u;
    u += 0x7fffu + ((u >> 16) & 1u);   // RNE
    return (u16)(u >> 16);
}

extern "C" __global__ void __launch_bounds__(256)
convert_weights(const float* __restrict__ qkv_w, const float* __restrict__ proj_w,
                u16* __restrict__ ws) {
    int i = (blockIdx.x * 256 + threadIdx.x) * 4;
    if (i >= QKVW_ELEMS + PROJW_ELEMS) return;
    const float* s = (i < QKVW_ELEMS) ? (qkv_w + i) : (proj_w + (i - QKVW_ELEMS));
    float4 v = *(const float4*)s;
    ushort4 o;
    o.x = f2bf(v.x); o.y = f2bf(v.y); o.z = f2bf(v.z); o.w = f2bf(v.w);
    *(ushort4*)(ws + i) = o;
}

// rope cos/sin table: one float4 = (cos a0, sin a0, cos a1, sin a1) per (h, t, pair-pair)
extern "C" __global__ void __launch_bounds__(256)
rope_table(const float* __restrict__ rfreq, float* __restrict__ tb) {
    int i = blockIdx.x * 256 + threadIdx.x;
    if (i >= TB_QUADS) return;
    int h = i / (NTOK * 8);
    int r = i % (NTOK * 8);
    int t = r >> 3;
    int p0 = (r & 7) * 2;
    float tx = (float)(t % 7), ty = (float)(t / 7);
    float a0 = tx * rfreq[h * 16 + p0]     + ty * rfreq[96 + h * 16 + p0];
    float a1 = tx * rfreq[h * 16 + p0 + 1] + ty * rfreq[96 + h * 16 + p0 + 1];
    float4 o;
    o.x = cosf(a0); o.y = sinf(a0);
    o.z = cosf(a1); o.w = sinf(a1);
    ((float4*)tb)[i] = o;
}

extern "C" __global__ void __launch_bounds__(256, 3)
fused_win_attn(const float* __restrict__ x, const float* __restrict__ mask,
               const u16* __restrict__ wsq, const float* __restrict__ qkv_b,
               const u16* __restrict__ wsp, const float* __restrict__ proj_b,
               const float* __restrict__ tb, float* __restrict__ out)
{
    __shared__ __align__(16) char smem[LDS_TOTAL];
    u16* xs = (u16*)(smem + XS_OFF);
    u16* ao = (u16*)(smem + AO_OFF);
    u16* bn = (u16*)(smem + BN_OFF);
    u16* ks = (u16*)(smem + KS_OFF);
    u16* ps = (u16*)(smem + PS_OFF);

    const int tid  = threadIdx.x;
    const int wave = tid >> 6;
    const int lane = tid & 63;
    const int ln   = lane & 15;
    const int quad = lane >> 4;
    const int blk  = blockIdx.x;
    const int widx = blk & (NWIN - 1);
    const float* xg = x + (long)blk * NTOK * DIM;
    const f32x4 fzero = {0.f, 0.f, 0.f, 0.f};
    const float2* tb2 = (const float2*)tb;
    const float scale = 0.17677669529663687f;  // 32^-0.5

    // V^T [192][64] bf16 lives in this block's own out slot (24576 of 37632 B)
    u16* vb = (u16*)out + (long)blk * (NTOK * DIM * 2);

    // mask -> 16 registers (reused across all 6 heads); -1e30 folds the m>=49 kill
    float mreg[4][4];
    #pragma unroll
    for (int nt = 0; nt < 4; nt++) {
        int m = nt * 16 + ln;
        #pragma unroll
        for (int r = 0; r < 4; r++) {
            int n = wave * 16 + quad * 4 + r;
            mreg[nt][r] = (m >= NTOK) ? -1e30f
                         : ((n < NTOK) ? mask[widx * (NTOK * NTOK) + n * NTOK + m] : 0.f);
        }
    }

    // ---- stage x -> xs (bf16), zero pad token rows 49..63 ----
    for (int i = tid; i < NTOK * 48; i += 256) {
        int r = i / 48, c = (i % 48) * 4;
        float4 v = *(const float4*)(xg + r * DIM + c);
        u16x4 o = { f2bf(v.x), f2bf(v.y), f2bf(v.z), f2bf(v.w) };
        *(u16x4*)(xs + r * 200 + c) = o;
    }
    {
        u16x8 zz = {0,0,0,0,0,0,0,0};
        for (int i = tid; i < 15 * 25; i += 256) {
            int r = 49 + i / 25, c = (i % 25) * 8;
            *(u16x8*)(xs + r * 200 + c) = zz;
        }
    }
    __syncthreads();   // (1)

    // ---- pass A: Q, token-split (each wave: own 16 tokens x 192 ch) ----
    // A = x tokens (own rows), B = weights  ->  C[m=token][n=channel]
    bf16x8 bfragA[6];
    #pragma unroll
    for (int kk = 0; kk < 6; kk++)
        bfragA[kk] = *(const bf16x8*)(xs + (wave * 16 + ln) * 200 + kk * 32 + quad * 8);

    for (int jt = 0; jt < 12; jt++) {
        bf16x8 af[6];
        const u16* wr = wsq + (jt * 16 + ln) * DIM + quad * 8;
        #pragma unroll
        for (int kk = 0; kk < 6; kk++) af[kk] = *(const bf16x8*)(wr + kk * 32);
        f32x4 acc = fzero;
        #pragma unroll
        for (int kk = 0; kk < 6; kk++)
            acc = __builtin_amdgcn_mfma_f32_16x16x32_bf16(bfragA[kk], af[kk], acc, 0, 0, 0);

        int ch = jt * 16 + ln;             // this lane's output channel
        int hh = jt >> 1;
        int p  = ((jt & 1) << 3) + (ln >> 1);
        float b = qkv_b[ch];
        float ssgn = (ln & 1) ? 1.f : -1.f;   // even lane: -sin ; odd lane: +sin
        #pragma unroll
        for (int r = 0; r < 4; r++) {
            int t = wave * 16 + quad * 4 + r;
            float v = acc[r] + b;
            float prt = __shfl_xor(v, 1);     // complex partner (ch^1)
            int tl = (t < NTOK) ? t : NTOK - 1;
            float2 cs = tb2[(hh * NTOK + tl) * 16 + p];
            float o = v * cs.x + prt * (ssgn * cs.y);
            if (t < NTOK) bn[t * 200 + ch] = f2bf(o * scale);
        }
    }
    // q fragments -> registers (own rows; same-wave LDS dep only)
    bf16x8 qreg[6];
    #pragma unroll
    for (int h = 0; h < 6; h++)
        qreg[h] = *(const bf16x8*)(bn + (wave * 16 + ln) * 200 + h * 32 + quad * 8);
    __syncthreads();   // (2) bounce region about to become ks

    // ---- pass B: K,V channel-split (original epilogue; B-frags re-read from xs) ----
    for (int jt = 12 + wave; jt < 36; jt += 4) {
        bf16x8 af[6];
        const u16* wr = wsq + (jt * 16 + ln) * DIM + quad * 8;
        #pragma unroll
        for (int kk = 0; kk < 6; kk++) af[kk] = *(const bf16x8*)(wr + kk * 32);
        f32x4 acc[4];
        #pragma unroll
        for (int nt = 0; nt < 4; nt++) acc[nt] = fzero;
        #pragma unroll
        for (int kk = 0; kk < 6; kk++)
            #pragma unroll
            for (int nt = 0; nt < 4; nt++) {
                bf16x8 bx = *(const bf16x8*)(xs + (nt * 16 + ln) * 200 + kk * 32 + quad * 8);
                acc[nt] = __builtin_amdgcn_mfma_f32_16x16x32_bf16(af[kk], bx, acc[nt], 0, 0, 0);
            }

        int j0 = jt * 16 + quad * 4;
        int isv = (jt >= 24);               // wave-uniform: 0=k 1=v
        int c0 = j0 % DIM;
        int hh = c0 >> 5;
        int p0 = (c0 & 31) >> 1;
        float b0 = qkv_b[j0],   b1 = qkv_b[j0+1];
        float b2 = qkv_b[j0+2], b3 = qkv_b[j0+3];
        #pragma unroll
        for (int nt = 0; nt < 4; nt++) {
            int t = nt * 16 + ln;
            float v0 = acc[nt][0] + b0;
            float v1 = acc[nt][1] + b1;
            float v2 = acc[nt][2] + b2;
            float v3 = acc[nt][3] + b3;
            if (!isv) {                     // K + rope, to LDS
                if (t < NTOK) {
                    float4 tv = ((const float4*)tb)[(hh * NTOK + t) * 8 + (p0 >> 1)];
                    float r0 = v0 * tv.x - v1 * tv.y;
                    float i0 = v0 * tv.y + v1 * tv.x;
                    float r1 = v2 * tv.z - v3 * tv.w;
                    float i1 = v2 * tv.w + v3 * tv.z;
                    u16x4 pk = { f2bf(r0), f2bf(i0), f2bf(r1), f2bf(i1) };
                    *(u16x4*)(ks + t * 200 + c0) = pk;
                }
            } else {                        // V^T [192][64] to own out slot
                float w0 = (t < NTOK) ? v0 : 0.f;
                float w1 = (t < NTOK) ? v1 : 0.f;
                float w2 = (t < NTOK) ? v2 : 0.f;
                float w3 = (t < NTOK) ? v3 : 0.f;
                vb[(c0+0)*64 + t] = f2bf(w0);
                vb[(c0+1)*64 + t] = f2bf(w1);
                vb[(c0+2)*64 + t] = f2bf(w2);
                vb[(c0+3)*64 + t] = f2bf(w3);
            }
        }
    }
    __syncthreads();   // (3) ks ready, vb drained; xs dead -> ao region live

    // ---- attention: q from regs, K from LDS, V from out slot; o -> ao ----
    #pragma unroll
    for (int h = 0; h < HEADS; h++) {
        f32x4 s4[4];
        #pragma unroll
        for (int nt = 0; nt < 4; nt++) {
            int krow = nt * 16 + ln; if (krow > NTOK - 1) krow = NTOK - 1;
            bf16x8 bk = *(const bf16x8*)(ks + krow * 200 + h * 32 + quad * 8);
            s4[nt] = __builtin_amdgcn_mfma_f32_16x16x32_bf16(qreg[h], bk, fzero, 0, 0, 0);
        }
        #pragma unroll
        for (int nt = 0; nt < 4; nt++)
            #pragma unroll
            for (int r = 0; r < 4; r++)
                s4[nt][r] += mreg[nt][r];
        float mx[4], sm[4], rs[4];
        #pragma unroll
        for (int r = 0; r < 4; r++) {
            float v = fmaxf(fmaxf(s4[0][r], s4[1][r]), fmaxf(s4[2][r], s4[3][r]));
            #pragma unroll
            for (int d = 1; d < 16; d <<= 1) v = fmaxf(v, __shfl_xor(v, d));
            mx[r] = v; sm[r] = 0.f;
        }
        #pragma unroll
        for (int nt = 0; nt < 4; nt++) {
            int m = nt * 16 + ln;
            #pragma unroll
            for (int r = 0; r < 4; r++) {
                float e = __expf(s4[nt][r] - mx[r]);
                sm[r] += e;
                int prow = wave * 16 + quad * 4 + r;
                if (prow < NTOK) ps[prow * 72 + m] = f2bf(e);
            }
        }
        #pragma unroll
        for (int r = 0; r < 4; r++) {
            float v = sm[r];
            #pragma unroll
            for (int d = 1; d < 16; d <<= 1) v += __shfl_xor(v, d);
            rs[r] = 1.0f / v;
        }
        f32x4 o0 = fzero, o1 = fzero;
        #pragma unroll
        for (int kk = 0; kk < 2; kk++) {
            int arow = wave * 16 + ln; if (arow > NTOK - 1) arow = NTOK - 1;
            bf16x8 ap  = *(const bf16x8*)(ps + arow * 72 + kk * 32 + quad * 8);
            bf16x8 bv0 = *(const bf16x8*)(vb + (h * 32 + ln) * 64      + kk * 32 + quad * 8);
            bf16x8 bv1 = *(const bf16x8*)(vb + (h * 32 + 16 + ln) * 64 + kk * 32 + quad * 8);
            o0 = __builtin_amdgcn_mfma_f32_16x16x32_bf16(ap, bv0, o0, 0, 0, 0);
            o1 = __builtin_amdgcn_mfma_f32_16x16x32_bf16(ap, bv1, o1, 0, 0, 0);
        }
        #pragma unroll
        for (int r = 0; r < 4; r++) {
            int t = wave * 16 + quad * 4 + r;
            if (t < NTOK) {
                ao[t * 200 + h * 32 + ln]      = f2bf(o0[r] * rs[r]);
                ao[t * 200 + h * 32 + 16 + ln] = f2bf(o1[r] * rs[r]);
            }
        }
    }
    __syncthreads();   // (4) all waves done reading vb before proj stores overwrite slot

    // ---- proj GEMM: A from own ao rows, weights from global, direct stores ----
    bf16x8 aa[6];
    int arow = wave * 16 + ln; if (arow > NTOK - 1) arow = NTOK - 1;
    #pragma unroll
    for (int kk = 0; kk < 6; kk++)
        aa[kk] = *(const bf16x8*)(ao + arow * 200 + kk * 32 + quad * 8);
    float* ob = out + (long)blk * (NTOK * DIM);
    for (int nt = 0; nt < 12; nt++) {
        const u16* wp = wsp + (nt * 16 + ln) * DIM + quad * 8;
        f32x4 p4 = fzero;
        #pragma unroll
        for (int kk = 0; kk < 6; kk++) {
            bf16x8 bw = *(const bf16x8*)(wp + kk * 32);
            p4 = __builtin_amdgcn_mfma_f32_16x16x32_bf16(aa[kk], bw, p4, 0, 0, 0);
        }
        float bb = proj_b[nt * 16 + ln];
        #pragma unroll
        for (int r = 0; r < 4; r++) {
            int t = wave * 16 + quad * 4 + r;
            if (t < NTOK) ob[t * DIM + nt * 16 + ln] = p4[r] + bb;
        }
    }
}

extern "C" void kernel_launch(void* const* d_in, const int* in_sizes, int n_in,
                              void* d_out, int out_size, void* d_ws, size_t ws_size,
                              hipStream_t stream) {
    (void)in_sizes; (void)n_in; (void)out_size; (void)ws_size;
    u16* ws = (u16*)d_ws;
    convert_weights<<<dim3((QKVW_ELEMS + PROJW_ELEMS) / 4 / 256 + 1), dim3(256), 0, stream>>>(
        (const float*)d_in[2], (const float*)d_in[4], ws);
    float* tb = (float*)((char*)d_ws + TB_OFF_BYTES);
    rope_table<<<dim3((TB_QUADS + 255) / 256), dim3(256), 0, stream>>>(
        (const float*)d_in[6], tb);
    fused_win_attn<<<dim3(NBLK), dim3(256), 0, stream>>>(
        (const float*)d_in[0], (const float*)d_in[1],
        ws, (const float*)d_in[3],
        ws + QKVW_ELEMS, (const float*)d_in[5],
        tb, (float*)d_out);
}